// Round 2
// baseline (221.149 us; speedup 1.0000x reference)
//
#include <hip/hip_runtime.h>

// Problem constants (fixed by the reference)
static constexpr int kB = 2;
static constexpr int kNV = 30000;
static constexpr int kD = 8;    // NDIRS
static constexpr int kR = 3;    // NRINGS
static constexpr int kC = 16;   // C
static constexpr int kF = 16;   // NF

typedef float v2f __attribute__((ext_vector_type(2)));

// One thread per (vertex, d_out). 8 consecutive lanes share a vertex.
__global__ __launch_bounds__(256) void sgc_kernel(
    const float* __restrict__ y,          // (B, NV, NDIRS, C)
    const int*   __restrict__ sync_field, // (B, NV, NRINGS, NDIRS, 3)
    const float* __restrict__ kern,       // (NRINGS, NDIRS, C, NF)
    const float* __restrict__ ck,         // (C, NF)
    const float* __restrict__ bias,       // (NF,)
    float*       __restrict__ out)        // (B, NV, NF)
{
    const int t    = blockIdx.x * blockDim.x + threadIdx.x;
    const int d    = t & 7;       // output direction
    const int bv   = t >> 3;      // flattened (b, v), 0..59999
    const int grpBase = (threadIdx.x & 63) & 56;  // first lane of 8-lane group

    // My gather element-offsets into y for (bv, r, d), r = 0..2.
    int myOfs[kR];
#pragma unroll
    for (int r = 0; r < kR; ++r) {
        const int* sf = sync_field + ((size_t)(bv * kR + r) * kD + d) * 3;
        const int bi = sf[0];
        const int vi = sf[1];
        const int di = sf[2];
        myOfs[r] = ((bi * kNV + vi) * kD + di) * kC;
    }

    // Accumulators: 16 fp32 as 8 packed float2 (bait v_pk_fma_f32).
    v2f acc[kF / 2];
#pragma unroll
    for (int j = 0; j < kF / 2; ++j) {
        acc[j].x = bias[2 * j];
        acc[j].y = bias[2 * j + 1];
    }

    // Circular conv: out[d,f] += sum_{r,dd,c} P[r,(d+dd)&7,c] * K[r,dd,c,f]
#pragma unroll
    for (int r = 0; r < kR; ++r) {
        const int o = myOfs[r];
#pragma unroll
        for (int dd = 0; dd < kD; ++dd) {
            const int src = grpBase | ((d + dd) & 7);
            const int ofs = __shfl(o, src, 64);
            float4 q[4];
            const float4* p4 = reinterpret_cast<const float4*>(y + ofs);
#pragma unroll
            for (int i = 0; i < 4; ++i) q[i] = p4[i];
            const float* pc = reinterpret_cast<const float*>(q);
            // K row block: wave-uniform address -> scalar loads
            const v2f* kr = reinterpret_cast<const v2f*>(
                kern + (size_t)(r * kD + dd) * kC * kF);
#pragma unroll
            for (int c = 0; c < kC; ++c) {
                const v2f pv = { pc[c], pc[c] };
#pragma unroll
                for (int j = 0; j < kF / 2; ++j)
                    acc[j] += pv * kr[c * (kF / 2) + j];
            }
        }
    }

    // Center term: y[b,v,d,:] @ center_kernel
    {
        float4 q[4];
        const float4* p4 =
            reinterpret_cast<const float4*>(y + (size_t)(bv * kD + d) * kC);
#pragma unroll
        for (int i = 0; i < 4; ++i) q[i] = p4[i];
        const float* pc = reinterpret_cast<const float*>(q);
        const v2f* kr = reinterpret_cast<const v2f*>(ck);
#pragma unroll
        for (int c = 0; c < kC; ++c) {
            const v2f pv = { pc[c], pc[c] };
#pragma unroll
            for (int j = 0; j < kF / 2; ++j)
                acc[j] += pv * kr[c * (kF / 2) + j];
        }
    }

    // ReLU, then max over the 8 directions (8-lane group reduction).
    float res[kF];
#pragma unroll
    for (int j = 0; j < kF / 2; ++j) {
        res[2 * j]     = fmaxf(acc[j].x, 0.0f);
        res[2 * j + 1] = fmaxf(acc[j].y, 0.0f);
    }
#pragma unroll
    for (int m = 1; m < 8; m <<= 1) {
#pragma unroll
        for (int f = 0; f < kF; ++f)
            res[f] = fmaxf(res[f], __shfl_xor(res[f], m, 64));
    }

    if (d == 0) {
        float4* o4 = reinterpret_cast<float4*>(out + (size_t)bv * kF);
#pragma unroll
        for (int i = 0; i < 4; ++i) {
            float4 v;
            v.x = res[4 * i + 0];
            v.y = res[4 * i + 1];
            v.z = res[4 * i + 2];
            v.w = res[4 * i + 3];
            o4[i] = v;
        }
    }
}

extern "C" void kernel_launch(void* const* d_in, const int* in_sizes, int n_in,
                              void* d_out, int out_size, void* d_ws, size_t ws_size,
                              hipStream_t stream) {
    const float* y    = reinterpret_cast<const float*>(d_in[0]);
    const int*   sf   = reinterpret_cast<const int*>(d_in[1]);
    const float* kern = reinterpret_cast<const float*>(d_in[2]);
    const float* ck   = reinterpret_cast<const float*>(d_in[3]);
    const float* bias = reinterpret_cast<const float*>(d_in[4]);
    float* out = reinterpret_cast<float*>(d_out);

    const int total = kB * kNV * kD;  // 480000 threads, 8 per vertex
    const int block = 256;
    const int grid  = total / block;  // 1875, exact (no tail)
    sgc_kernel<<<grid, block, 0, stream>>>(y, sf, kern, ck, bias, out);
}